// Round 12
// baseline (380.437 us; speedup 1.0000x reference)
//
#include <hip/hip_runtime.h>
#include <hip/hip_fp16.h>
#include <math.h>

#define NEG_SLOPE 0.2f

typedef _Float16 half8 __attribute__((ext_vector_type(8)));
typedef float f32x4 __attribute__((ext_vector_type(4)));

// ---------------- fused prep: cvt(x), cvt(W1), count ----------------
__global__ __launch_bounds__(256) void prep_k(const float* __restrict__ x,
                                              const float* __restrict__ W1,
                                              const int* __restrict__ ei,
                                              __half* __restrict__ x16,
                                              __half* __restrict__ w16,
                                              int* __restrict__ deg,
                                              int N, int E, int nbx, int nbw) {
  int b = blockIdx.x;
  if (b < nbx) {
    int i = b * 256 + threadIdx.x;
    if (i < N * 32) {
      float4 v = ((const float4*)x)[i];
      __half2 lo = __floats2half2_rn(v.x, v.y);
      __half2 hi = __floats2half2_rn(v.z, v.w);
      uint2 pk;
      pk.x = *(unsigned int*)&lo;
      pk.y = *(unsigned int*)&hi;
      ((uint2*)x16)[i] = pk;
    }
  } else if (b < nbx + nbw) {
    int i = (b - nbx) * 256 + threadIdx.x;
    if (i < 512 * 128 / 4) {
      float4 v = ((const float4*)W1)[i];
      __half2 lo = __floats2half2_rn(v.x, v.y);
      __half2 hi = __floats2half2_rn(v.z, v.w);
      uint2 pk;
      pk.x = *(unsigned int*)&lo;
      pk.y = *(unsigned int*)&hi;
      ((uint2*)w16)[i] = pk;
    }
  } else {
    int i = (b - nbx - nbw) * 256 + threadIdx.x;
    if (i < E + N) {
      int dst = (i < E) ? ei[E + i] : (i - E);
      atomicAdd(&deg[dst], 1);
    }
  }
}

// ---------------- hierarchical scan ----------------
__global__ __launch_bounds__(256) void scan1_k(const int* __restrict__ deg, int* __restrict__ off,
                                               int* __restrict__ sums, int N) {
  __shared__ int buf[256];
  int t = threadIdx.x, i = blockIdx.x * 256 + t;
  int v = (i < N) ? deg[i] : 0;
  buf[t] = v;
  __syncthreads();
#pragma unroll
  for (int ofs = 1; ofs < 256; ofs <<= 1) {
    int add = (t >= ofs) ? buf[t - ofs] : 0;
    __syncthreads();
    buf[t] += add;
    __syncthreads();
  }
  if (i < N) off[i] = buf[t] - v;
  if (t == 255) sums[blockIdx.x] = buf[t];
}

__global__ __launch_bounds__(1024) void scan2_k(int* __restrict__ sums, int nb) {
  __shared__ int buf[1024];
  int t = threadIdx.x;
  int v = (t < nb) ? sums[t] : 0;
  buf[t] = v;
  __syncthreads();
#pragma unroll
  for (int ofs = 1; ofs < 1024; ofs <<= 1) {
    int add = (t >= ofs) ? buf[t - ofs] : 0;
    __syncthreads();
    buf[t] += add;
    __syncthreads();
  }
  if (t < nb) sums[t] = buf[t] - v;
}

__global__ __launch_bounds__(256) void scan3_k(int* __restrict__ off, const int* __restrict__ sums,
                                               int* __restrict__ cursor, int N, int TOT) {
  int i = blockIdx.x * 256 + threadIdx.x;
  if (i < N) {
    int v = off[i] + sums[blockIdx.x];
    off[i] = v;
    cursor[i] = v;
  }
  if (i == 0) off[N] = TOT;
}

__global__ void fill_k(const int* __restrict__ ei, int E, int N,
                       int* __restrict__ cursor, int* __restrict__ csr) {
  int i = blockIdx.x * 256 + threadIdx.x;
  if (i >= E + N) return;
  int src, dst;
  if (i < E) { src = ei[i]; dst = ei[E + i]; }
  else       { src = i - E; dst = src; }
  int pos = atomicAdd(&cursor[dst], 1);
  csr[pos] = src;
}

// ---------------- GEMM1 via MFMA f16, stripe per block, coalesced h1 stores ----------------
__global__ __launch_bounds__(256) void gemm1_k(const __half* __restrict__ x16,
                                               const __half* __restrict__ w16,
                                               const float* __restrict__ a_src1,
                                               const float* __restrict__ a_dst1,
                                               __half* __restrict__ h1,
                                               float* __restrict__ as1,
                                               float* __restrict__ ad1, int N) {
  __shared__ __half Bs[64 * 128];    // 16 KB, 16B-XOR-swizzled by row
  __shared__ __half tb[4][16][72];   // per-wave transpose buffer (row stride 144B, 16B-aligned)
  const int tid = threadIdx.x;
  const int bm = blockIdx.x * 64;
  const int w = tid >> 6, lane = tid & 63;
  const int l15 = lane & 15;
  const int kg = lane >> 4;          // A k-group == D row-group
  int arow = bm + w * 16 + l15;
  const __half* xr = x16 + ((size_t)(arow < N ? arow : 0) << 7);

  half8 afr[4];
#pragma unroll
  for (int ks = 0; ks < 4; ++ks) afr[ks] = *(const half8*)(xr + ks * 32 + kg * 8);

  float as_[4] = {0.f, 0.f, 0.f, 0.f};
  float ad_[4] = {0.f, 0.f, 0.f, 0.f};

  const int srow = lane >> 2;          // store: row within wave's 16
  const int scol = (lane & 3) * 16;    // store: col block
  const int grow_store = bm + w * 16 + srow;

  for (int bt = 0; bt < 8; ++bt) {
    const int bn = bt * 64;
#pragma unroll
    for (int i = 0; i < 4; ++i) {
      int e8 = i * 256 + tid;
      int r = e8 >> 4, c16 = e8 & 15;
      int swz = ((r << 8) | (c16 << 4)) ^ ((r & 7) << 4);
      *(uint4*)((char*)Bs + swz) = *(const uint4*)(w16 + ((size_t)(bn + r) << 7) + (c16 << 3));
    }
    __syncthreads();

    f32x4 acc[4];
#pragma unroll
    for (int ns = 0; ns < 4; ++ns) acc[ns] = (f32x4){0.f, 0.f, 0.f, 0.f};
#pragma unroll
    for (int ks = 0; ks < 4; ++ks) {
      int kb = (ks * 32 + kg * 8) << 1;
#pragma unroll
      for (int ns = 0; ns < 4; ++ns) {
        int r = ns * 16 + l15;
        half8 b = *(const half8*)((char*)Bs + (((r << 8) | kb) ^ ((r & 7) << 4)));
        acc[ns] = __builtin_amdgcn_mfma_f32_16x16x32_f16(afr[ks], b, acc[ns], 0, 0, 0);
      }
    }

    // attention-half accumulation (from regs)
    const int head = bt >> 1;
#pragma unroll
    for (int ns = 0; ns < 4; ++ns) {
      float av = a_src1[head * 128 + (bn & 127) + ns * 16 + l15];
      float dv = a_dst1[head * 128 + (bn & 127) + ns * 16 + l15];
#pragma unroll
      for (int r = 0; r < 4; ++r) {
        float v = acc[ns][r];
        as_[r] = fmaf(v, av, as_[r]);
        ad_[r] = fmaf(v, dv, ad_[r]);
      }
    }

    // transpose via wave-private LDS, then coalesced 16B h1 stores
#pragma unroll
    for (int ns = 0; ns < 4; ++ns)
#pragma unroll
      for (int r = 0; r < 4; ++r)
        tb[w][kg * 4 + r][ns * 16 + l15] = __float2half(acc[ns][r]);
    if (grow_store < N) {
      uint4 p0 = *(const uint4*)&tb[w][srow][scol];
      uint4 p1 = *(const uint4*)&tb[w][srow][scol + 8];
      __half* hp = h1 + ((size_t)grow_store << 9) + bn + scol;
      *(uint4*)hp = p0;
      *(uint4*)(hp + 8) = p1;
    }

    if (bt & 1) {   // head complete -> reduce over l15, direct store
#pragma unroll
      for (int r = 0; r < 4; ++r) {
#pragma unroll
        for (int ofs = 1; ofs < 16; ofs <<= 1) {
          as_[r] += __shfl_xor(as_[r], ofs);
          ad_[r] += __shfl_xor(ad_[r], ofs);
        }
        int grow = bm + w * 16 + kg * 4 + r;
        if (l15 == 0 && grow < N) {
          as1[(size_t)grow * 4 + head] = as_[r];
          ad1[(size_t)grow * 4 + head] = ad_[r];
        }
        as_[r] = 0.f;
        ad_[r] = 0.f;
      }
    }
    __syncthreads();
  }
}

// ---------------- layer-1 aggregate + bias/ELU + fused GEMM2 -> nd2 record ----------------
// nd2[n][16] = [as2(4) | h2(8) | ad2(4)] floats, 64B-aligned per node.
__global__ __launch_bounds__(256) void agg1_k(const __half* __restrict__ h1,
                                              const float* __restrict__ as1,
                                              const float* __restrict__ ad1,
                                              const int* __restrict__ off,
                                              const int* __restrict__ csr,
                                              const float* __restrict__ b1,
                                              const float* __restrict__ W2,
                                              const float* __restrict__ a_src2,
                                              const float* __restrict__ a_dst2,
                                              float* __restrict__ nd2, int N) {
  int n = blockIdx.x * 4 + (threadIdx.x >> 6);
  int lane = threadIdx.x & 63;
  if (n >= N) return;
  int row = off[n], end = off[n + 1];
  float4 adn = *(const float4*)(ad1 + (size_t)n * 4);
  const int hh = lane >> 4;
  const float adh = hh == 0 ? adn.x : hh == 1 ? adn.y : hh == 2 ? adn.z : adn.w;
  const int cb = lane * 8;

  float a0 = 0.f, a1 = 0.f, a2 = 0.f, a3 = 0.f, a4 = 0.f, a5 = 0.f, a6 = 0.f, a7 = 0.f;
  float z = 0.f;
  int idx = row;
  for (; idx + 4 <= end; idx += 4) {
    int s0 = csr[idx], s1 = csr[idx + 1], s2 = csr[idx + 2], s3 = csr[idx + 3];
    float e0 = as1[(size_t)s0 * 4 + hh];
    float e1 = as1[(size_t)s1 * 4 + hh];
    float e2 = as1[(size_t)s2 * 4 + hh];
    float e3 = as1[(size_t)s3 * 4 + hh];
    uint4 u0 = *(const uint4*)(h1 + (size_t)s0 * 512 + cb);
    uint4 u1 = *(const uint4*)(h1 + (size_t)s1 * 512 + cb);
    uint4 u2 = *(const uint4*)(h1 + (size_t)s2 * 512 + cb);
    uint4 u3 = *(const uint4*)(h1 + (size_t)s3 * 512 + cb);
    e0 += adh; e0 = e0 > 0.f ? e0 : NEG_SLOPE * e0; float q0 = __expf(e0);
    e1 += adh; e1 = e1 > 0.f ? e1 : NEG_SLOPE * e1; float q1 = __expf(e1);
    e2 += adh; e2 = e2 > 0.f ? e2 : NEG_SLOPE * e2; float q2 = __expf(e2);
    e3 += adh; e3 = e3 > 0.f ? e3 : NEG_SLOPE * e3; float q3 = __expf(e3);
    z += q0 + q1 + q2 + q3;
    const __half* hv;
    hv = (const __half*)&u0;
    a0 = fmaf(q0, __half2float(hv[0]), a0); a1 = fmaf(q0, __half2float(hv[1]), a1);
    a2 = fmaf(q0, __half2float(hv[2]), a2); a3 = fmaf(q0, __half2float(hv[3]), a3);
    a4 = fmaf(q0, __half2float(hv[4]), a4); a5 = fmaf(q0, __half2float(hv[5]), a5);
    a6 = fmaf(q0, __half2float(hv[6]), a6); a7 = fmaf(q0, __half2float(hv[7]), a7);
    hv = (const __half*)&u1;
    a0 = fmaf(q1, __half2float(hv[0]), a0); a1 = fmaf(q1, __half2float(hv[1]), a1);
    a2 = fmaf(q1, __half2float(hv[2]), a2); a3 = fmaf(q1, __half2float(hv[3]), a3);
    a4 = fmaf(q1, __half2float(hv[4]), a4); a5 = fmaf(q1, __half2float(hv[5]), a5);
    a6 = fmaf(q1, __half2float(hv[6]), a6); a7 = fmaf(q1, __half2float(hv[7]), a7);
    hv = (const __half*)&u2;
    a0 = fmaf(q2, __half2float(hv[0]), a0); a1 = fmaf(q2, __half2float(hv[1]), a1);
    a2 = fmaf(q2, __half2float(hv[2]), a2); a3 = fmaf(q2, __half2float(hv[3]), a3);
    a4 = fmaf(q2, __half2float(hv[4]), a4); a5 = fmaf(q2, __half2float(hv[5]), a5);
    a6 = fmaf(q2, __half2float(hv[6]), a6); a7 = fmaf(q2, __half2float(hv[7]), a7);
    hv = (const __half*)&u3;
    a0 = fmaf(q3, __half2float(hv[0]), a0); a1 = fmaf(q3, __half2float(hv[1]), a1);
    a2 = fmaf(q3, __half2float(hv[2]), a2); a3 = fmaf(q3, __half2float(hv[3]), a3);
    a4 = fmaf(q3, __half2float(hv[4]), a4); a5 = fmaf(q3, __half2float(hv[5]), a5);
    a6 = fmaf(q3, __half2float(hv[6]), a6); a7 = fmaf(q3, __half2float(hv[7]), a7);
  }
  for (; idx < end; ++idx) {
    int s = csr[idx];
    float e = as1[(size_t)s * 4 + hh] + adh;
    e = e > 0.f ? e : NEG_SLOPE * e;
    float q = __expf(e);
    z += q;
    uint4 u = *(const uint4*)(h1 + (size_t)s * 512 + cb);
    const __half* hv = (const __half*)&u;
    a0 = fmaf(q, __half2float(hv[0]), a0); a1 = fmaf(q, __half2float(hv[1]), a1);
    a2 = fmaf(q, __half2float(hv[2]), a2); a3 = fmaf(q, __half2float(hv[3]), a3);
    a4 = fmaf(q, __half2float(hv[4]), a4); a5 = fmaf(q, __half2float(hv[5]), a5);
    a6 = fmaf(q, __half2float(hv[6]), a6); a7 = fmaf(q, __half2float(hv[7]), a7);
  }

  float inv = 1.f / z;
  const float4* bp = (const float4*)(b1 + cb);
  float4 bb0 = bp[0], bb1 = bp[1];
  float hl[8];
  float o;
  o = fmaf(a0, inv, bb0.x); hl[0] = o > 0.f ? o : expm1f(o);
  o = fmaf(a1, inv, bb0.y); hl[1] = o > 0.f ? o : expm1f(o);
  o = fmaf(a2, inv, bb0.z); hl[2] = o > 0.f ? o : expm1f(o);
  o = fmaf(a3, inv, bb0.w); hl[3] = o > 0.f ? o : expm1f(o);
  o = fmaf(a4, inv, bb1.x); hl[4] = o > 0.f ? o : expm1f(o);
  o = fmaf(a5, inv, bb1.y); hl[5] = o > 0.f ? o : expm1f(o);
  o = fmaf(a6, inv, bb1.z); hl[6] = o > 0.f ? o : expm1f(o);
  o = fmaf(a7, inv, bb1.w); hl[7] = o > 0.f ? o : expm1f(o);

  float oo[8];
#pragma unroll
  for (int k = 0; k < 8; ++k) {
    const float4* wp = (const float4*)(W2 + (size_t)k * 512 + cb);
    float4 w0 = wp[0], w1 = wp[1];
    oo[k] = hl[0] * w0.x + hl[1] * w0.y + hl[2] * w0.z + hl[3] * w0.w +
            hl[4] * w1.x + hl[5] * w1.y + hl[6] * w1.z + hl[7] * w1.w;
  }
#pragma unroll
  for (int ofs = 1; ofs < 64; ofs <<= 1) {
#pragma unroll
    for (int k = 0; k < 8; ++k) oo[k] += __shfl_xor(oo[k], ofs);
  }
  if (lane == 0) {
    float* nd = nd2 + (size_t)n * 16;
    float4 asv, adv;
    asv.x = oo[0] * a_src2[0] + oo[1] * a_src2[1];
    asv.y = oo[2] * a_src2[2] + oo[3] * a_src2[3];
    asv.z = oo[4] * a_src2[4] + oo[5] * a_src2[5];
    asv.w = oo[6] * a_src2[6] + oo[7] * a_src2[7];
    adv.x = oo[0] * a_dst2[0] + oo[1] * a_dst2[1];
    adv.y = oo[2] * a_dst2[2] + oo[3] * a_dst2[3];
    adv.z = oo[4] * a_dst2[4] + oo[5] * a_dst2[5];
    adv.w = oo[6] * a_dst2[6] + oo[7] * a_dst2[7];
    *(float4*)(nd)      = asv;
    *(float4*)(nd + 4)  = make_float4(oo[0], oo[1], oo[2], oo[3]);
    *(float4*)(nd + 8)  = make_float4(oo[4], oo[5], oo[6], oo[7]);
    *(float4*)(nd + 12) = adv;
  }
}

// ---------------- layer-2 aggregate (single-line 48B gathers) ----------------
__global__ __launch_bounds__(256) void agg2_k(const float* __restrict__ nd2,
                                              const int* __restrict__ off,
                                              const int* __restrict__ csr,
                                              const float* __restrict__ b2,
                                              float* __restrict__ out, int N) {
  int n = blockIdx.x * 4 + (threadIdx.x >> 6);
  int lane = threadIdx.x & 63;
  if (n >= N) return;
  int row = off[n], end = off[n + 1];
  float4 adn = *(const float4*)(nd2 + (size_t)n * 16 + 12);

  float z0 = 0.f, z1 = 0.f, z2 = 0.f, z3 = 0.f;
  float c0 = 0.f, c1 = 0.f, c2 = 0.f, c3 = 0.f, c4 = 0.f, c5 = 0.f, c6 = 0.f, c7 = 0.f;
  for (int idx = row + lane; idx < end; idx += 64) {
    int s = csr[idx];
    const float* ns_ = nd2 + (size_t)s * 16;
    float4 av = *(const float4*)(ns_);
    float4 v0 = *(const float4*)(ns_ + 4);
    float4 v1 = *(const float4*)(ns_ + 8);
    float e, p;
    e = av.x + adn.x; e = e > 0.f ? e : NEG_SLOPE * e; p = __expf(e); z0 += p;
    c0 = fmaf(p, v0.x, c0); c1 = fmaf(p, v0.y, c1);
    e = av.y + adn.y; e = e > 0.f ? e : NEG_SLOPE * e; p = __expf(e); z1 += p;
    c2 = fmaf(p, v0.z, c2); c3 = fmaf(p, v0.w, c3);
    e = av.z + adn.z; e = e > 0.f ? e : NEG_SLOPE * e; p = __expf(e); z2 += p;
    c4 = fmaf(p, v1.x, c4); c5 = fmaf(p, v1.y, c5);
    e = av.w + adn.w; e = e > 0.f ? e : NEG_SLOPE * e; p = __expf(e); z3 += p;
    c6 = fmaf(p, v1.z, c6); c7 = fmaf(p, v1.w, c7);
  }
#pragma unroll
  for (int ofs = 1; ofs < 64; ofs <<= 1) {
    z0 += __shfl_xor(z0, ofs); z1 += __shfl_xor(z1, ofs);
    z2 += __shfl_xor(z2, ofs); z3 += __shfl_xor(z3, ofs);
    c0 += __shfl_xor(c0, ofs); c1 += __shfl_xor(c1, ofs);
    c2 += __shfl_xor(c2, ofs); c3 += __shfl_xor(c3, ofs);
    c4 += __shfl_xor(c4, ofs); c5 += __shfl_xor(c5, ofs);
    c6 += __shfl_xor(c6, ofs); c7 += __shfl_xor(c7, ofs);
  }
  if (lane == 0) {
    float o0 = 0.25f * (c0 / z0 + c2 / z1 + c4 / z2 + c6 / z3) + b2[0];
    float o1 = 0.25f * (c1 / z0 + c3 / z1 + c5 / z2 + c7 / z3) + b2[1];
    out[(size_t)n * 2]     = o0;
    out[(size_t)n * 2 + 1] = o1;
  }
}

// ---------------- host ----------------
extern "C" void kernel_launch(void* const* d_in, const int* in_sizes, int n_in,
                              void* d_out, int out_size, void* d_ws, size_t ws_size,
                              hipStream_t stream) {
  const float* x      = (const float*)d_in[0];
  const int*   ei     = (const int*)d_in[1];
  const float* W1     = (const float*)d_in[2];
  const float* a_src1 = (const float*)d_in[3];
  const float* a_dst1 = (const float*)d_in[4];
  const float* b1     = (const float*)d_in[5];
  const float* W2     = (const float*)d_in[6];
  const float* a_src2 = (const float*)d_in[7];
  const float* a_dst2 = (const float*)d_in[8];
  const float* b2     = (const float*)d_in[9];
  float* out = (float*)d_out;

  const int N = in_sizes[0] / 128;
  const int E = in_sizes[1] / 2;
  const int TOT = E + N;

  char* ws = (char*)d_ws;
  auto alloc = [&](size_t bytes) {
    char* p = ws;
    ws += (bytes + 511) & ~(size_t)511;
    return p;
  };
  __half* h1    = (__half*)alloc((size_t)N * 512 * 2);
  __half* x16   = (__half*)alloc((size_t)N * 128 * 2);
  __half* w16   = (__half*)alloc((size_t)512 * 128 * 2);
  float* as1    = (float*)alloc((size_t)N * 4 * 4);
  float* ad1    = (float*)alloc((size_t)N * 4 * 4);
  float* nd2    = (float*)alloc((size_t)N * 16 * 4);   // [as2|h2|ad2], 64B/node
  int*   deg    = (int*)alloc((size_t)N * 4);
  int*   off    = (int*)alloc((size_t)(N + 1) * 4);
  int*   cursor = (int*)alloc((size_t)N * 4);
  int*   csr    = (int*)alloc((size_t)TOT * 4);
  int*   sums   = (int*)alloc((size_t)1024 * 4);

  const int eb    = (TOT + 255) / 256;
  const int nb256 = (N + 255) / 256;
  const int nwb   = (N + 3) / 4;
  const int nbx   = (N * 32 + 255) / 256;       // x cvt blocks (N*128/4 quads)
  const int nbw   = (512 * 128 / 4 + 255) / 256; // W1 cvt blocks

  hipMemsetAsync(deg, 0, (size_t)N * 4, stream);

  prep_k<<<nbx + nbw + eb, 256, 0, stream>>>(x, W1, ei, x16, w16, deg, N, E, nbx, nbw);
  scan1_k<<<nb256, 256, 0, stream>>>(deg, off, sums, N);
  scan2_k<<<1, 1024, 0, stream>>>(sums, nb256);
  scan3_k<<<nb256, 256, 0, stream>>>(off, sums, cursor, N, TOT);
  fill_k<<<eb, 256, 0, stream>>>(ei, E, N, cursor, csr);

  gemm1_k<<<(N + 63) / 64, 256, 0, stream>>>(x16, w16, a_src1, a_dst1,
                                             h1, as1, ad1, N);
  agg1_k<<<nwb, 256, 0, stream>>>(h1, as1, ad1, off, csr, b1,
                                  W2, a_src2, a_dst2, nd2, N);
  agg2_k<<<nwb, 256, 0, stream>>>(nd2, off, csr, b2, out, N);
}